// Round 1
// baseline (245.608 us; speedup 1.0000x reference)
//
#include <hip/hip_runtime.h>

// LDPC sum-product BP decode, (3,6)-regular, N=8192, R=4096, B=1024, 10 iters.
//
// R6: persistent-LDS — one workgroup per batch element, all state in LDS.
// R7: 1024 threads, per-thread check ownership, prev state in registers.
// R8 LESSON: never subtract near-equal large products; clamp before ratios.
// R10: exp-domain state (E_s = e^tot, q_s = e^c2v): zero exp/log in hot loop.
// R11 LESSON: ballot-scan build = 4096 x 24576 scan = ~150us. Reverted.
// R12: two dispatches, zero memsets (mod-6 atomic slots + 12-comparator sort).
// R13 LESSON: fusing build into persistent kernel replicates it 1024x. Two
//      dispatches is optimal; harness overhead (~58us) is dispatch-invariant.
// R14: q-only own-state. Key identity: next-iter own message
//        t = (E*hn - hd)/(E*hn + hd)  with hn/hd = 1/q  ==>  t = (E-q)/(E+q).
//      Drops hn/hd (48 regs -> 24), drops A=E*hn mul + 2 reg writes per edge.
//      Freed registers + __launch_bounds__(1024,4) (LDS caps us at 1 block/CU
//      = 4 waves/SIMD anyway, so 128 VGPRs are free) let the compiler hoist
//      all 48 graph-random LDS byte addresses out of the iteration loop.
//      E_s declared FIRST (LDS base 0: read addr = vidx*4, no base add);
//      q_s at 32768 fits the 16-bit ds offset immediate.
//
// All ranges audited finite: E in [2e-15, 5e14], q in [5e-4, 1999]. No NaN.

#define N_  8192
#define R_  4096
#define DV_ 3
#define DC_ 6
#define E_  (N_ * DV_)
#define B_  1024
#define ITERS_ 10

#define THREADS_ 1024
#define CPT_ (R_ / THREADS_)   // 4 checks per thread
#define VPT_ (N_ / THREADS_)   // 8 variables per thread

#define LOG2E_ 1.442695041f
#define LN2_   0.69314718f

// Scatter edges into per-check rows. counters is UNINITIALIZED scratch: the
// 6 returns per check are consecutive, so ret%6 covers slots 0..5 exactly.
// Row content order is nondeterministic; persistent_kernel sorts each row.
__global__ __launch_bounds__(256) void build_edges_kernel(
    const int* __restrict__ edge_check, unsigned int* __restrict__ counters,
    int* __restrict__ check_edges) {
  int e = blockIdx.x * 256 + threadIdx.x;
  if (e < E_) {
    int r = edge_check[e];
    unsigned int ret = atomicAdd(&counters[r], 1u);
    check_edges[r * DC_ + (ret % 6u)] = e;
  }
}

// Persistent exp-domain BP: block b decodes batch element b entirely in LDS.
// E_s[v] = e^{tot[v]}, q_s[e] = e^{c2v[e]} (var-major, e = 3v+j).
__global__ __launch_bounds__(THREADS_, 4) void persistent_kernel(
    const float* __restrict__ recv, const int* __restrict__ check_edges,
    float* __restrict__ out) {
  __shared__ float E_s[N_];  // 32 KB, e^{tot}; base 0 -> addr = vidx*4
  __shared__ float q_s[E_];  // 96 KB, e^{c2v}; base 32768 -> 16-bit ds offset
  const int b = blockIdx.x;
  const int tid = threadIdx.x;
  const float* r = recv + (size_t)b * N_;

  // This thread's 4 check rows -> registers; sort each row ascending
  // (12-comparator optimal network) so the table is deterministic and
  // bit-identical to the sorted-atomic builds of R3..R10.
  int eidx[CPT_][DC_];
  int vidx[CPT_][DC_];
#pragma unroll
  for (int c = 0; c < CPT_; c++) {
    int rr = c * THREADS_ + tid;
    int e0 = check_edges[rr * DC_ + 0], e1 = check_edges[rr * DC_ + 1];
    int e2 = check_edges[rr * DC_ + 2], e3 = check_edges[rr * DC_ + 3];
    int e4 = check_edges[rr * DC_ + 4], e5 = check_edges[rr * DC_ + 5];
#define CSWAP(a, b) { int lo = min(a, b), hi = max(a, b); a = lo; b = hi; }
    CSWAP(e0, e5) CSWAP(e1, e3) CSWAP(e2, e4)
    CSWAP(e1, e2) CSWAP(e3, e4)
    CSWAP(e0, e3) CSWAP(e2, e5)
    CSWAP(e0, e1) CSWAP(e2, e3) CSWAP(e4, e5)
    CSWAP(e1, e2) CSWAP(e3, e4)
#undef CSWAP
    eidx[c][0] = e0; eidx[c][1] = e1; eidx[c][2] = e2;
    eidx[c][3] = e3; eidx[c][4] = e4; eidx[c][5] = e5;
#pragma unroll
    for (int i = 0; i < DC_; i++)
      vidx[c][i] = (int)((unsigned)eidx[c][i] / 3u);  // edge_var[e] == e/3
  }

  // Own previous c2v output in exp domain: q = e^{c2v}; c2v=0 <=> q=1.
  float qown[CPT_][DC_];
#pragma unroll
  for (int c = 0; c < CPT_; c++)
#pragma unroll
    for (int i = 0; i < DC_; i++) qown[c][i] = 1.0f;

  // e^{llr} per owned var (llr = 2*recv); the only exps in the kernel.
  float e_llr[VPT_];
#pragma unroll
  for (int k = 0; k < VPT_; k++) {
    float llr = 2.0f * r[tid + k * THREADS_];
    e_llr[k] = __builtin_amdgcn_exp2f(llr * LOG2E_);
    E_s[tid + k * THREADS_] = e_llr[k];
  }
  __syncthreads();

  for (int iter = 0; iter < ITERS_; iter++) {
    // ---- check phase: t = tanh((tot - c2v_prev)/2) = (E - q)/(E + q),
    // since e^{tot-c2v} = E/q. den = E+q strictly positive. ----
#pragma unroll
    for (int c = 0; c < CPT_; c++) {
      float t[DC_];
#pragma unroll
      for (int i = 0; i < DC_; i++) {
        float E = E_s[vidx[c][i]];
        float q = qown[c][i];
        t[i] = (E - q) * __builtin_amdgcn_rcpf(E + q);
      }
      // leave-one-out products via prefix/suffix (division-free, |t|<=1+eps)
      float loo[DC_];
      float run = 1.0f;
#pragma unroll
      for (int i = 0; i < DC_; i++) { loo[i] = run; run *= t[i]; }
      run = 1.0f;
#pragma unroll
      for (int i = DC_ - 1; i >= 0; i--) { loo[i] *= run; run *= t[i]; }
#pragma unroll
      for (int i = 0; i < DC_; i++) {
        // clamp FIRST (reference clip semantics; keeps 1-y >= 0.001 > 0)
        float y = loo[i];
        y = fminf(fmaxf(y, -0.999f), 0.999f);
        float qq = (1.0f + y) * __builtin_amdgcn_rcpf(1.0f - y);  // e^{c2v}
        q_s[eidx[c][i]] = qq;
        qown[c][i] = qq;
      }
    }
    __syncthreads();
    // ---- variable phase: E = e^{llr} * q0*q1*q2; q0,q1 paired into one
    // ds_read2_b32 (4B-aligned float2), q2 single. ----
#pragma unroll
    for (int k = 0; k < VPT_; k++) {
      int v = tid + k * THREADS_;
      float2 q01;
      __builtin_memcpy(&q01, &q_s[3 * v], sizeof(float2));
      float q2 = q_s[3 * v + 2];
      E_s[v] = ((e_llr[k] * q01.x) * q01.y) * q2;
    }
    __syncthreads();
  }

  // ---- output: LLR = ln(E); bits = (LLR < 0); [B,N] layout ----
  const size_t BN = (size_t)B_ * N_;
#pragma unroll
  for (int k = 0; k < VPT_; k++) {
    int n = tid + k * THREADS_;
    float val = LN2_ * __builtin_amdgcn_logf(E_s[n]);  // E in [2e-15,5e14]
    out[(size_t)b * N_ + n] = val;
    out[BN + (size_t)b * N_ + n] = (val < 0.0f) ? 1.0f : 0.0f;
  }
}

extern "C" void kernel_launch(void* const* d_in, const int* in_sizes, int n_in,
                              void* d_out, int out_size, void* d_ws,
                              size_t ws_size, hipStream_t stream) {
  const float* recv = (const float*)d_in[0];     // [B, N]
  const int* edge_check = (const int*)d_in[2];   // [E]
  float* out = (float*)d_out;

  char* ws = (char*)d_ws;
  unsigned int* counters = (unsigned int*)ws;           // 16 KB, UNINITIALIZED
  int* check_edges = (int*)(ws + (size_t)R_ * sizeof(unsigned int));  // 96 KB

  build_edges_kernel<<<(E_ + 255) / 256, 256, 0, stream>>>(edge_check, counters,
                                                           check_edges);
  persistent_kernel<<<B_, THREADS_, 0, stream>>>(recv, check_edges, out);
}

// Round 2
// 242.636 us; speedup vs baseline: 1.0122x; 1.0122x over previous
//
#include <hip/hip_runtime.h>

// LDPC sum-product BP decode, (3,6)-regular, N=8192, R=4096, B=1024, 10 iters.
//
// R6: persistent-LDS — one workgroup per batch element, all state in LDS.
// R7: 1024 threads, per-thread check ownership, prev state in registers.
// R8 LESSON: never subtract near-equal large products; clamp before ratios.
// R10: exp-domain state (E_s = e^tot, q_s = e^c2v): zero exp/log in hot loop.
// R11 LESSON: ballot-scan build = 4096 x 24576 scan = ~150us. Reverted.
// R12: two dispatches, zero memsets (mod-6 atomic slots + 12-comparator sort).
// R13 LESSON: fusing build into persistent kernel replicates it 1024x.
// R14: q-only own-state (t = (E-q)/(E+q)). VALUBusy 57->54.5, dur flat,
//      VGPR stuck at 64 => bottleneck is LDS-load serialization under a
//      64-reg budget, not VALU.
// R15: wide-batch loads. Both phases restructured load-all -> compute ->
//      store-all with named register arrays (static indices, no scratch).
//      With launch_bounds(1024,4) the 128-VGPR budget lets all 24 random
//      E-reads stay in flight (one lgkm drain instead of many grouped
//      waits), overlapping LDS latency + conflict cycles. LDS caps us at
//      1 block/CU = 4 waves/SIMD regardless, so VGPR growth is free.
//      Math bit-identical to R14 (absmax 0.03125).
// PRECISION NOTE (R14 analysis): f16/bf16 message storage is inadmissible.
//      Quantization adds ABSOLUTE LLR error ~1e-2; ~42K samples have
//      |LLR_ref| < 0.03, so sign flips hit the bits plane -> absmax 1.0.
//      Only relative-error-preserving transforms allowed.
//
// All ranges audited finite: E in [2e-15, 5e14], q in [5e-4, 1999]. No NaN.

#define N_  8192
#define R_  4096
#define DV_ 3
#define DC_ 6
#define E_  (N_ * DV_)
#define B_  1024
#define ITERS_ 10

#define THREADS_ 1024
#define CPT_ (R_ / THREADS_)   // 4 checks per thread
#define VPT_ (N_ / THREADS_)   // 8 variables per thread

#define LOG2E_ 1.442695041f
#define LN2_   0.69314718f

// Scatter edges into per-check rows. counters is UNINITIALIZED scratch: the
// 6 returns per check are consecutive, so ret%6 covers slots 0..5 exactly.
// Row content order is nondeterministic; persistent_kernel sorts each row.
__global__ __launch_bounds__(256) void build_edges_kernel(
    const int* __restrict__ edge_check, unsigned int* __restrict__ counters,
    int* __restrict__ check_edges) {
  int e = blockIdx.x * 256 + threadIdx.x;
  if (e < E_) {
    int r = edge_check[e];
    unsigned int ret = atomicAdd(&counters[r], 1u);
    check_edges[r * DC_ + (ret % 6u)] = e;
  }
}

// Persistent exp-domain BP: block b decodes batch element b entirely in LDS.
// E_s[v] = e^{tot[v]}, q_s[e] = e^{c2v[e]} (var-major, e = 3v+j).
__global__ __launch_bounds__(THREADS_, 4) void persistent_kernel(
    const float* __restrict__ recv, const int* __restrict__ check_edges,
    float* __restrict__ out) {
  __shared__ float E_s[N_];  // 32 KB, e^{tot}
  __shared__ float q_s[E_];  // 96 KB, e^{c2v}
  const int b = blockIdx.x;
  const int tid = threadIdx.x;
  const float* r = recv + (size_t)b * N_;

  // This thread's 4 check rows -> registers; sort each row ascending
  // (12-comparator optimal network) so the table is deterministic and
  // bit-identical to the sorted-atomic builds of R3..R10.
  int eidx[CPT_][DC_];
  int vidx[CPT_][DC_];
#pragma unroll
  for (int c = 0; c < CPT_; c++) {
    int rr = c * THREADS_ + tid;
    int e0 = check_edges[rr * DC_ + 0], e1 = check_edges[rr * DC_ + 1];
    int e2 = check_edges[rr * DC_ + 2], e3 = check_edges[rr * DC_ + 3];
    int e4 = check_edges[rr * DC_ + 4], e5 = check_edges[rr * DC_ + 5];
#define CSWAP(a, b) { int lo = min(a, b), hi = max(a, b); a = lo; b = hi; }
    CSWAP(e0, e5) CSWAP(e1, e3) CSWAP(e2, e4)
    CSWAP(e1, e2) CSWAP(e3, e4)
    CSWAP(e0, e3) CSWAP(e2, e5)
    CSWAP(e0, e1) CSWAP(e2, e3) CSWAP(e4, e5)
    CSWAP(e1, e2) CSWAP(e3, e4)
#undef CSWAP
    eidx[c][0] = e0; eidx[c][1] = e1; eidx[c][2] = e2;
    eidx[c][3] = e3; eidx[c][4] = e4; eidx[c][5] = e5;
#pragma unroll
    for (int i = 0; i < DC_; i++)
      vidx[c][i] = (int)((unsigned)eidx[c][i] / 3u);  // edge_var[e] == e/3
  }

  // Own previous c2v output in exp domain: q = e^{c2v}; c2v=0 <=> q=1.
  float qown[CPT_][DC_];
#pragma unroll
  for (int c = 0; c < CPT_; c++)
#pragma unroll
    for (int i = 0; i < DC_; i++) qown[c][i] = 1.0f;

  // e^{llr} per owned var (llr = 2*recv); the only exps in the kernel.
  float e_llr[VPT_];
#pragma unroll
  for (int k = 0; k < VPT_; k++) {
    float llr = 2.0f * r[tid + k * THREADS_];
    e_llr[k] = __builtin_amdgcn_exp2f(llr * LOG2E_);
    E_s[tid + k * THREADS_] = e_llr[k];
  }
  __syncthreads();

  for (int iter = 0; iter < ITERS_; iter++) {
    // ---- check phase, stage 1: batch-load ALL 24 random E values so the
    // ds_reads issue back-to-back and their latency/conflicts overlap. ----
    float Ev[CPT_][DC_];
#pragma unroll
    for (int c = 0; c < CPT_; c++)
#pragma unroll
      for (int i = 0; i < DC_; i++)
        Ev[c][i] = E_s[vidx[c][i]];

    // ---- check phase, stage 2: t = (E - q)/(E + q) (= tanh((tot-c2v)/2)),
    // leave-one-out products, clamp, write q. den strictly positive. ----
#pragma unroll
    for (int c = 0; c < CPT_; c++) {
      float t[DC_];
#pragma unroll
      for (int i = 0; i < DC_; i++) {
        float q = qown[c][i];
        t[i] = (Ev[c][i] - q) * __builtin_amdgcn_rcpf(Ev[c][i] + q);
      }
      // leave-one-out products via prefix/suffix (division-free, |t|<=1+eps)
      float loo[DC_];
      float run = 1.0f;
#pragma unroll
      for (int i = 0; i < DC_; i++) { loo[i] = run; run *= t[i]; }
      run = 1.0f;
#pragma unroll
      for (int i = DC_ - 1; i >= 0; i--) { loo[i] *= run; run *= t[i]; }
#pragma unroll
      for (int i = 0; i < DC_; i++) {
        // clamp FIRST (reference clip semantics; keeps 1-y >= 0.001 > 0)
        float y = loo[i];
        y = fminf(fmaxf(y, -0.999f), 0.999f);
        float qq = (1.0f + y) * __builtin_amdgcn_rcpf(1.0f - y);  // e^{c2v}
        q_s[eidx[c][i]] = qq;
        qown[c][i] = qq;
      }
    }
    __syncthreads();

    // ---- variable phase: batch-load all 24 q words (8x ds_read2_b32 +
    // 8x ds_read_b32), then multiply and store. ----
    float2 q01[VPT_];
    float q2[VPT_];
#pragma unroll
    for (int k = 0; k < VPT_; k++) {
      int v = tid + k * THREADS_;
      __builtin_memcpy(&q01[k], &q_s[3 * v], sizeof(float2));
      q2[k] = q_s[3 * v + 2];
    }
#pragma unroll
    for (int k = 0; k < VPT_; k++) {
      int v = tid + k * THREADS_;
      E_s[v] = ((e_llr[k] * q01[k].x) * q01[k].y) * q2[k];
    }
    __syncthreads();
  }

  // ---- output: LLR = ln(E); bits = (LLR < 0); [B,N] layout ----
  const size_t BN = (size_t)B_ * N_;
#pragma unroll
  for (int k = 0; k < VPT_; k++) {
    int n = tid + k * THREADS_;
    float val = LN2_ * __builtin_amdgcn_logf(E_s[n]);  // E in [2e-15,5e14]
    out[(size_t)b * N_ + n] = val;
    out[BN + (size_t)b * N_ + n] = (val < 0.0f) ? 1.0f : 0.0f;
  }
}

extern "C" void kernel_launch(void* const* d_in, const int* in_sizes, int n_in,
                              void* d_out, int out_size, void* d_ws,
                              size_t ws_size, hipStream_t stream) {
  const float* recv = (const float*)d_in[0];     // [B, N]
  const int* edge_check = (const int*)d_in[2];   // [E]
  float* out = (float*)d_out;

  char* ws = (char*)d_ws;
  unsigned int* counters = (unsigned int*)ws;           // 16 KB, UNINITIALIZED
  int* check_edges = (int*)(ws + (size_t)R_ * sizeof(unsigned int));  // 96 KB

  build_edges_kernel<<<(E_ + 255) / 256, 256, 0, stream>>>(edge_check, counters,
                                                           check_edges);
  persistent_kernel<<<B_, THREADS_, 0, stream>>>(recv, check_edges, out);
}

// Round 3
// 234.591 us; speedup vs baseline: 1.0470x; 1.0343x over previous
//
#include <hip/hip_runtime.h>

// LDPC sum-product BP decode, (3,6)-regular, N=8192, R=4096, B=1024, 10 iters.
//
// R6: persistent-LDS — one workgroup per batch element, all state in LDS.
// R7: 1024 threads, per-thread check ownership, prev state in registers.
// R8 LESSON: never subtract near-equal large products; clamp before ratios.
// R10: exp-domain state (E_s = e^tot, q_s = e^c2v): zero exp/log in hot loop.
// R11 LESSON: ballot-scan build = 4096 x 24576 scan = ~150us. Reverted.
// R12: two dispatches, zero memsets (mod-6 atomic slots + 12-comparator sort).
// R13 LESSON: fusing build into persistent kernel replicates it 1024x.
// R14: q-only own-state (t = (E-q)/(E+q)). VALUBusy 57->54.5, dur flat.
// R15 LESSON: C++-level "batch load" does NOT bind — VGPR stayed 64, dur
//      flat. LLVM re-interleaves loads/uses to minimize pressure; the 24
//      random E-reads still issue in small groups with a wait per group.
// R16: inline-asm batched gather. 24 back-to-back volatile ds_read_b32
//      (volatile asms keep program order) + ONE s_waitcnt lgkmcnt(0) +
//      sched_barrier(0) (rule 18: compiler doesn't track asm DS ops, so
//      the explicit wait is mandatory; sched_barrier pins consumers).
//      LDS byte addresses precomputed once (AS3 ptr truncates to 32-bit
//      LDS offset). Writes stay C++ so the compiler's own pre-barrier
//      waitcnt still covers them. Forces ~100 VGPRs live (legal at 4
//      waves/SIMD per __launch_bounds__(1024,4); LDS caps us at 1
//      block/CU anyway).
// PRECISION NOTE: f16/bf16 message storage is inadmissible. Quantization
//      adds ABSOLUTE LLR error ~1e-2; many samples have |LLR_ref| < 0.03,
//      sign flips would hit the bits plane -> absmax 1.0. Only
//      relative-error-preserving transforms allowed.
//
// All ranges audited finite: E in [2e-15, 5e14], q in [5e-4, 1999]. No NaN.

#define N_  8192
#define R_  4096
#define DV_ 3
#define DC_ 6
#define E_  (N_ * DV_)
#define B_  1024
#define ITERS_ 10

#define THREADS_ 1024
#define CPT_ (R_ / THREADS_)   // 4 checks per thread
#define VPT_ (N_ / THREADS_)   // 8 variables per thread

#define LOG2E_ 1.442695041f
#define LN2_   0.69314718f

// LDS byte offset of a __shared__ location. Generic pointers to LDS are
// {shared_aperture_hi32 | 32-bit offset}; truncation yields the ds_read
// address. (Standard HK/CK idiom on gfx9+.)
__device__ __forceinline__ unsigned lds_off(const void* p) {
  return (unsigned)(unsigned long long)p;
}

// Scatter edges into per-check rows. counters is UNINITIALIZED scratch: the
// 6 returns per check are consecutive, so ret%6 covers slots 0..5 exactly.
// Row content order is nondeterministic; persistent_kernel sorts each row.
__global__ __launch_bounds__(256) void build_edges_kernel(
    const int* __restrict__ edge_check, unsigned int* __restrict__ counters,
    int* __restrict__ check_edges) {
  int e = blockIdx.x * 256 + threadIdx.x;
  if (e < E_) {
    int r = edge_check[e];
    unsigned int ret = atomicAdd(&counters[r], 1u);
    check_edges[r * DC_ + (ret % 6u)] = e;
  }
}

// Persistent exp-domain BP: block b decodes batch element b entirely in LDS.
// E_s[v] = e^{tot[v]}, q_s[e] = e^{c2v[e]} (var-major, e = 3v+j).
__global__ __launch_bounds__(THREADS_, 4) void persistent_kernel(
    const float* __restrict__ recv, const int* __restrict__ check_edges,
    float* __restrict__ out) {
  __shared__ float E_s[N_];  // 32 KB, e^{tot}
  __shared__ float q_s[E_];  // 96 KB, e^{c2v}
  const int b = blockIdx.x;
  const int tid = threadIdx.x;
  const float* r = recv + (size_t)b * N_;

  // This thread's 4 check rows -> registers; sort each row ascending
  // (12-comparator optimal network) so the table is deterministic and
  // bit-identical to the sorted-atomic builds of R3..R10.
  int eidx[CPT_][DC_];
#pragma unroll
  for (int c = 0; c < CPT_; c++) {
    int rr = c * THREADS_ + tid;
    int e0 = check_edges[rr * DC_ + 0], e1 = check_edges[rr * DC_ + 1];
    int e2 = check_edges[rr * DC_ + 2], e3 = check_edges[rr * DC_ + 3];
    int e4 = check_edges[rr * DC_ + 4], e5 = check_edges[rr * DC_ + 5];
#define CSWAP(a, b) { int lo = min(a, b), hi = max(a, b); a = lo; b = hi; }
    CSWAP(e0, e5) CSWAP(e1, e3) CSWAP(e2, e4)
    CSWAP(e1, e2) CSWAP(e3, e4)
    CSWAP(e0, e3) CSWAP(e2, e5)
    CSWAP(e0, e1) CSWAP(e2, e3) CSWAP(e4, e5)
    CSWAP(e1, e2) CSWAP(e3, e4)
#undef CSWAP
    eidx[c][0] = e0; eidx[c][1] = e1; eidx[c][2] = e2;
    eidx[c][3] = e3; eidx[c][4] = e4; eidx[c][5] = e5;
  }

  // Precomputed LDS byte addresses: E-read addr (4 * (e/3)), loop-invariant.
  unsigned raddr[CPT_][DC_];
#pragma unroll
  for (int c = 0; c < CPT_; c++)
#pragma unroll
    for (int i = 0; i < DC_; i++)
      raddr[c][i] = lds_off(&E_s[(unsigned)eidx[c][i] / 3u]);

  // Own previous c2v output in exp domain: q = e^{c2v}; c2v=0 <=> q=1.
  float qown[CPT_][DC_];
#pragma unroll
  for (int c = 0; c < CPT_; c++)
#pragma unroll
    for (int i = 0; i < DC_; i++) qown[c][i] = 1.0f;

  // e^{llr} per owned var (llr = 2*recv); the only exps in the kernel.
  float e_llr[VPT_];
#pragma unroll
  for (int k = 0; k < VPT_; k++) {
    float llr = 2.0f * r[tid + k * THREADS_];
    e_llr[k] = __builtin_amdgcn_exp2f(llr * LOG2E_);
    E_s[tid + k * THREADS_] = e_llr[k];
  }
  __syncthreads();

  for (int iter = 0; iter < ITERS_; iter++) {
    // ---- check phase, stage 1: ALL 24 random E-reads issued back-to-back
    // (volatile asm preserves order), ONE lgkm drain. Latency + conflict
    // cycles of all 24 overlap instead of serializing in small groups. ----
    float Ev[CPT_][DC_];
#pragma unroll
    for (int c = 0; c < CPT_; c++)
#pragma unroll
      for (int i = 0; i < DC_; i++)
        asm volatile("ds_read_b32 %0, %1"
                     : "=v"(Ev[c][i])
                     : "v"(raddr[c][i]));
    asm volatile("s_waitcnt lgkmcnt(0)" ::: "memory");
    __builtin_amdgcn_sched_barrier(0);

    // ---- check phase, stage 2: t = (E - q)/(E + q) (= tanh((tot-c2v)/2)),
    // leave-one-out products, clamp, write q. den strictly positive. ----
#pragma unroll
    for (int c = 0; c < CPT_; c++) {
      float t[DC_];
#pragma unroll
      for (int i = 0; i < DC_; i++) {
        float q = qown[c][i];
        t[i] = (Ev[c][i] - q) * __builtin_amdgcn_rcpf(Ev[c][i] + q);
      }
      // leave-one-out products via prefix/suffix (division-free, |t|<=1+eps)
      float loo[DC_];
      float run = 1.0f;
#pragma unroll
      for (int i = 0; i < DC_; i++) { loo[i] = run; run *= t[i]; }
      run = 1.0f;
#pragma unroll
      for (int i = DC_ - 1; i >= 0; i--) { loo[i] *= run; run *= t[i]; }
#pragma unroll
      for (int i = 0; i < DC_; i++) {
        // clamp FIRST (reference clip semantics; keeps 1-y >= 0.001 > 0)
        float y = loo[i];
        y = fminf(fmaxf(y, -0.999f), 0.999f);
        float qq = (1.0f + y) * __builtin_amdgcn_rcpf(1.0f - y);  // e^{c2v}
        q_s[eidx[c][i]] = qq;   // plain C++ write: compiler tracks it for
        qown[c][i] = qq;        // the pre-barrier lgkmcnt drain
      }
    }
    __syncthreads();

    // ---- variable phase: E = e^{llr} * q0*q1*q2; q0,q1 paired into one
    // ds_read2_b32 (4B-aligned float2), q2 single. Stride-3 word pattern
    // is coprime to 32 banks -> near conflict-free; leave in C++. ----
#pragma unroll
    for (int k = 0; k < VPT_; k++) {
      int v = tid + k * THREADS_;
      float2 q01;
      __builtin_memcpy(&q01, &q_s[3 * v], sizeof(float2));
      float q2 = q_s[3 * v + 2];
      E_s[v] = ((e_llr[k] * q01.x) * q01.y) * q2;
    }
    __syncthreads();
  }

  // ---- output: LLR = ln(E); bits = (LLR < 0); [B,N] layout ----
  const size_t BN = (size_t)B_ * N_;
#pragma unroll
  for (int k = 0; k < VPT_; k++) {
    int n = tid + k * THREADS_;
    float val = LN2_ * __builtin_amdgcn_logf(E_s[n]);  // E in [2e-15,5e14]
    out[(size_t)b * N_ + n] = val;
    out[BN + (size_t)b * N_ + n] = (val < 0.0f) ? 1.0f : 0.0f;
  }
}

extern "C" void kernel_launch(void* const* d_in, const int* in_sizes, int n_in,
                              void* d_out, int out_size, void* d_ws,
                              size_t ws_size, hipStream_t stream) {
  const float* recv = (const float*)d_in[0];     // [B, N]
  const int* edge_check = (const int*)d_in[2];   // [E]
  float* out = (float*)d_out;

  char* ws = (char*)d_ws;
  unsigned int* counters = (unsigned int*)ws;           // 16 KB, UNINITIALIZED
  int* check_edges = (int*)(ws + (size_t)R_ * sizeof(unsigned int));  // 96 KB

  build_edges_kernel<<<(E_ + 255) / 256, 256, 0, stream>>>(edge_check, counters,
                                                           check_edges);
  persistent_kernel<<<B_, THREADS_, 0, stream>>>(recv, check_edges, out);
}

// Round 4
// 231.952 us; speedup vs baseline: 1.0589x; 1.0114x over previous
//
#include <hip/hip_runtime.h>

// LDPC sum-product BP decode, (3,6)-regular, N=8192, R=4096, B=1024, 10 iters.
//
// R6: persistent-LDS — one workgroup per batch element, all state in LDS.
// R7: 1024 threads, per-thread check ownership, prev state in registers.
// R8 LESSON: never subtract near-equal large products; clamp before ratios.
// R10: exp-domain state (E_s = e^tot, q_s = e^c2v): zero exp/log in hot loop.
// R11 LESSON: ballot-scan build = 4096 x 24576 scan = ~150us. Reverted.
// R12: two dispatches, zero memsets (mod-6 atomic slots + 12-comparator sort).
// R13 LESSON: fusing build into persistent kernel replicates it 1024x.
// R14: q-only own-state (t = (E-q)/(E+q)).
// R15/R16 LESSON: load scheduling within a wave is NOT the bottleneck —
//      compiler-grouped waits (R15) == single-wait batched asm gather (R16)
//      == 176us. Counters: LDS busy ~6.1K cy/block-iter (2.3K issue + 3.8K
//      conflict), VALU ~5.8K, total 10.56K ~= SUM -> pipes are serialized
//      by the barrier convoy: post-__syncthreads all 16 waves storm LDS
//      together (VALU idle), then all compute together (LDS idle).
// R17: per-check counted pipeline (T3/T4 at check granularity). Check phase
//      becomes: issue 6 reads for check c+1; s_waitcnt lgkmcnt(K) with K
//      counted so only check c's reads are known-complete (DS completes
//      in-order; writes counted too: K = 6,12,12,6, final drain 0); compute
//      check c; issue its 6 asm writes. Fine-grain LDS/VALU interleave per
//      wave -> across 4 waves/SIMD the pipes fill instead of alternating
//      storms. sched_barrier(0) after each wait (rule 18); explicit
//      lgkmcnt(0) before __syncthreads (compiler can't see asm writes).
//      Math/order/addresses bit-identical (absmax must stay 0.03125).
// PRECISION NOTE: f16/bf16 message storage is inadmissible. Quantization
//      adds ABSOLUTE LLR error ~1e-2; many samples have |LLR_ref| < 0.03,
//      sign flips would hit the bits plane -> absmax 1.0. Only
//      relative-error-preserving transforms allowed.
//
// All ranges audited finite: E in [2e-15, 5e14], q in [5e-4, 1999]. No NaN.

#define N_  8192
#define R_  4096
#define DV_ 3
#define DC_ 6
#define E_  (N_ * DV_)
#define B_  1024
#define ITERS_ 10

#define THREADS_ 1024
#define CPT_ (R_ / THREADS_)   // 4 checks per thread
#define VPT_ (N_ / THREADS_)   // 8 variables per thread

#define LOG2E_ 1.442695041f
#define LN2_   0.69314718f

// LDS byte offset of a __shared__ location. Generic pointers to LDS are
// {shared_aperture_hi32 | 32-bit offset}; truncation yields the ds address.
__device__ __forceinline__ unsigned lds_off(const void* p) {
  return (unsigned)(unsigned long long)p;
}

// Scatter edges into per-check rows. counters is UNINITIALIZED scratch: the
// 6 returns per check are consecutive, so ret%6 covers slots 0..5 exactly.
// Row content order is nondeterministic; persistent_kernel sorts each row.
__global__ __launch_bounds__(256) void build_edges_kernel(
    const int* __restrict__ edge_check, unsigned int* __restrict__ counters,
    int* __restrict__ check_edges) {
  int e = blockIdx.x * 256 + threadIdx.x;
  if (e < E_) {
    int r = edge_check[e];
    unsigned int ret = atomicAdd(&counters[r], 1u);
    check_edges[r * DC_ + (ret % 6u)] = e;
  }
}

// Issue 6 back-to-back ds_read_b32 (volatile asm preserves mutual order;
// results NOT ready until an explicit s_waitcnt lgkmcnt).
__device__ __forceinline__ void issue_reads6(float dst[DC_],
                                             const unsigned ra[DC_]) {
  asm volatile("ds_read_b32 %0, %1" : "=v"(dst[0]) : "v"(ra[0]));
  asm volatile("ds_read_b32 %0, %1" : "=v"(dst[1]) : "v"(ra[1]));
  asm volatile("ds_read_b32 %0, %1" : "=v"(dst[2]) : "v"(ra[2]));
  asm volatile("ds_read_b32 %0, %1" : "=v"(dst[3]) : "v"(ra[3]));
  asm volatile("ds_read_b32 %0, %1" : "=v"(dst[4]) : "v"(ra[4]));
  asm volatile("ds_read_b32 %0, %1" : "=v"(dst[5]) : "v"(ra[5]));
}

// One check update: t = (E-q)/(E+q), leave-one-out products, clamp, write
// q_s via asm (6 ds_write_b32, counted in the caller's lgkm budget).
// Bit-identical math/order to R14..R16.
__device__ __forceinline__ void compute_check(const float Ev[DC_],
                                              float qo[DC_],
                                              const unsigned wa[DC_]) {
  float t[DC_];
#pragma unroll
  for (int i = 0; i < DC_; i++)
    t[i] = (Ev[i] - qo[i]) * __builtin_amdgcn_rcpf(Ev[i] + qo[i]);
  float loo[DC_];
  float run = 1.0f;
#pragma unroll
  for (int i = 0; i < DC_; i++) { loo[i] = run; run *= t[i]; }
  run = 1.0f;
#pragma unroll
  for (int i = DC_ - 1; i >= 0; i--) { loo[i] *= run; run *= t[i]; }
#pragma unroll
  for (int i = 0; i < DC_; i++) {
    // clamp FIRST (reference clip semantics; keeps 1-y >= 0.001 > 0)
    float y = loo[i];
    y = fminf(fmaxf(y, -0.999f), 0.999f);
    float qq = (1.0f + y) * __builtin_amdgcn_rcpf(1.0f - y);  // e^{c2v}
    asm volatile("ds_write_b32 %0, %1" :: "v"(wa[i]), "v"(qq));
    qo[i] = qq;
  }
}

// Persistent exp-domain BP: block b decodes batch element b entirely in LDS.
// E_s[v] = e^{tot[v]}, q_s[e] = e^{c2v[e]} (var-major, e = 3v+j).
__global__ __launch_bounds__(THREADS_, 4) void persistent_kernel(
    const float* __restrict__ recv, const int* __restrict__ check_edges,
    float* __restrict__ out) {
  __shared__ float E_s[N_];  // 32 KB, e^{tot}
  __shared__ float q_s[E_];  // 96 KB, e^{c2v}
  const int b = blockIdx.x;
  const int tid = threadIdx.x;
  const float* r = recv + (size_t)b * N_;

  // This thread's 4 check rows -> registers; sort each row ascending
  // (12-comparator optimal network) so the table is deterministic and
  // bit-identical to the sorted-atomic builds of R3..R10.
  int eidx[CPT_][DC_];
#pragma unroll
  for (int c = 0; c < CPT_; c++) {
    int rr = c * THREADS_ + tid;
    int e0 = check_edges[rr * DC_ + 0], e1 = check_edges[rr * DC_ + 1];
    int e2 = check_edges[rr * DC_ + 2], e3 = check_edges[rr * DC_ + 3];
    int e4 = check_edges[rr * DC_ + 4], e5 = check_edges[rr * DC_ + 5];
#define CSWAP(a, b) { int lo = min(a, b), hi = max(a, b); a = lo; b = hi; }
    CSWAP(e0, e5) CSWAP(e1, e3) CSWAP(e2, e4)
    CSWAP(e1, e2) CSWAP(e3, e4)
    CSWAP(e0, e3) CSWAP(e2, e5)
    CSWAP(e0, e1) CSWAP(e2, e3) CSWAP(e4, e5)
    CSWAP(e1, e2) CSWAP(e3, e4)
#undef CSWAP
    eidx[c][0] = e0; eidx[c][1] = e1; eidx[c][2] = e2;
    eidx[c][3] = e3; eidx[c][4] = e4; eidx[c][5] = e5;
  }

  // Precomputed LDS byte addresses (loop-invariant):
  //   raddr = &E_s[e/3] (edge_var[e] == e/3), waddr = &q_s[e].
  unsigned raddr[CPT_][DC_], waddr[CPT_][DC_];
#pragma unroll
  for (int c = 0; c < CPT_; c++)
#pragma unroll
    for (int i = 0; i < DC_; i++) {
      raddr[c][i] = lds_off(&E_s[(unsigned)eidx[c][i] / 3u]);
      waddr[c][i] = lds_off(&q_s[eidx[c][i]]);
    }

  // Own previous c2v output in exp domain: q = e^{c2v}; c2v=0 <=> q=1.
  float qown[CPT_][DC_];
#pragma unroll
  for (int c = 0; c < CPT_; c++)
#pragma unroll
    for (int i = 0; i < DC_; i++) qown[c][i] = 1.0f;

  // e^{llr} per owned var (llr = 2*recv); the only exps in the kernel.
  float e_llr[VPT_];
#pragma unroll
  for (int k = 0; k < VPT_; k++) {
    float llr = 2.0f * r[tid + k * THREADS_];
    e_llr[k] = __builtin_amdgcn_exp2f(llr * LOG2E_);
    E_s[tid + k * THREADS_] = e_llr[k];
  }
  __syncthreads();

  for (int iter = 0; iter < ITERS_; iter++) {
    // ---- check phase: 4-stage per-check pipeline with counted lgkm waits.
    // DS ops complete in-order; issue sequence is
    //   R0(6) R1(6) W0(6) R2(6) W1(6) R3(6) W2(6) W3(6)
    // so the wait budgets below guarantee exactly check c's reads. ----
    float Ev0[DC_], Ev1[DC_], Ev2[DC_], Ev3[DC_];
    issue_reads6(Ev0, raddr[0]);

    issue_reads6(Ev1, raddr[1]);                       // issued 12
    asm volatile("s_waitcnt lgkmcnt(6)" ::: "memory"); // R0 done
    __builtin_amdgcn_sched_barrier(0);
    compute_check(Ev0, qown[0], waddr[0]);             // +W0 -> issued 18

    issue_reads6(Ev2, raddr[2]);                       // issued 24
    asm volatile("s_waitcnt lgkmcnt(12)" ::: "memory");// >=12 done: R1 done
    __builtin_amdgcn_sched_barrier(0);
    compute_check(Ev1, qown[1], waddr[1]);             // +W1 -> issued 30

    issue_reads6(Ev3, raddr[3]);                       // issued 36
    asm volatile("s_waitcnt lgkmcnt(12)" ::: "memory");// >=24 done: R2 done
    __builtin_amdgcn_sched_barrier(0);
    compute_check(Ev2, qown[2], waddr[2]);             // +W2 -> issued 42

    asm volatile("s_waitcnt lgkmcnt(6)" ::: "memory"); // >=36 done: R3 done
    __builtin_amdgcn_sched_barrier(0);
    compute_check(Ev3, qown[3], waddr[3]);             // +W3 -> issued 48

    // Drain OUR asm writes before the barrier: the compiler's own pre-barrier
    // waitcnt only covers ops it tracks, and these are invisible to it.
    asm volatile("s_waitcnt lgkmcnt(0)" ::: "memory");
    __syncthreads();

    // ---- variable phase: E = e^{llr} * q0*q1*q2; q0,q1 paired into one
    // ds_read2_b32 (4B-aligned float2), q2 single. Stride-3 word pattern
    // is 2-way-per-bank max (free); leave in C++. ----
#pragma unroll
    for (int k = 0; k < VPT_; k++) {
      int v = tid + k * THREADS_;
      float2 q01;
      __builtin_memcpy(&q01, &q_s[3 * v], sizeof(float2));
      float q2 = q_s[3 * v + 2];
      E_s[v] = ((e_llr[k] * q01.x) * q01.y) * q2;
    }
    __syncthreads();
  }

  // ---- output: LLR = ln(E); bits = (LLR < 0); [B,N] layout ----
  const size_t BN = (size_t)B_ * N_;
#pragma unroll
  for (int k = 0; k < VPT_; k++) {
    int n = tid + k * THREADS_;
    float val = LN2_ * __builtin_amdgcn_logf(E_s[n]);  // E in [2e-15,5e14]
    out[(size_t)b * N_ + n] = val;
    out[BN + (size_t)b * N_ + n] = (val < 0.0f) ? 1.0f : 0.0f;
  }
}

extern "C" void kernel_launch(void* const* d_in, const int* in_sizes, int n_in,
                              void* d_out, int out_size, void* d_ws,
                              size_t ws_size, hipStream_t stream) {
  const float* recv = (const float*)d_in[0];     // [B, N]
  const int* edge_check = (const int*)d_in[2];   // [E]
  float* out = (float*)d_out;

  char* ws = (char*)d_ws;
  unsigned int* counters = (unsigned int*)ws;           // 16 KB, UNINITIALIZED
  int* check_edges = (int*)(ws + (size_t)R_ * sizeof(unsigned int));  // 96 KB

  build_edges_kernel<<<(E_ + 255) / 256, 256, 0, stream>>>(edge_check, counters,
                                                           check_edges);
  persistent_kernel<<<B_, THREADS_, 0, stream>>>(recv, check_edges, out);
}

// Round 10
// 231.539 us; speedup vs baseline: 1.0608x; 1.0018x over previous
//
#include <hip/hip_runtime.h>

// LDPC sum-product BP decode, (3,6)-regular, N=8192, R=4096, B=1024, 10 iters.
//
// R6: persistent-LDS — one workgroup per batch element, all state in LDS.
// R7: 1024 threads, per-thread check ownership, prev state in registers.
// R8 LESSON: never subtract near-equal large products; clamp before ratios.
// R10: exp-domain state (E_s = e^tot, q_s = e^c2v): zero exp/log in hot loop.
// R12: two dispatches, zero memsets (mod-6 atomic slots + 12-comparator sort).
// R14: q-only own-state (t = (E-q)/(E+q)).
// R15/R16 LESSON: load scheduling within a wave is NOT the bottleneck —
//      batched asm gather == compiler grouping == 176us.
// R17 WIN (-6%): per-check counted pipeline (issue reads c+1; lgkmcnt(K)
//      counted; compute c; asm writes). Partial LDS/VALU overlap.
// R18: pin the 48 loop-invariant LDS addresses. At VGPR=60 the compiler
//      REMATERIALIZES all 48 addrs every iteration (magic-mul e/3 + shifts
//      ~150-200 VALU/thread-iter) — that's why VALUBusy (58%) is ~2x the
//      hand-counted math. Opaque asm touch ("+v") makes each addr
//      non-rematerializable -> must stay resident; launch_bounds(1024,4)
//      allows 128 VGPRs (live set ~114). Plus v_med3_f32 clamp (bit-
//      identical to fmin/fmax for finite y). Math order unchanged.
//      [R5-R9 infra failures (container death, 4x acquisition timeout).
//      SIXTH submission of the same kernel — it has never run.]
// PRECISION NOTE: f16/bf16 message storage is inadmissible. Quantization
//      adds ABSOLUTE LLR error ~1e-2; many samples have |LLR_ref| < 0.03,
//      sign flips would hit the bits plane -> absmax 1.0. Only
//      relative-error-preserving transforms allowed.
//
// All ranges audited finite: E in [2e-15, 5e14], q in [5e-4, 1999]. No NaN.

#define N_  8192
#define R_  4096
#define DV_ 3
#define DC_ 6
#define E_  (N_ * DV_)
#define B_  1024
#define ITERS_ 10

#define THREADS_ 1024
#define CPT_ (R_ / THREADS_)   // 4 checks per thread
#define VPT_ (N_ / THREADS_)   // 8 variables per thread

#define LOG2E_ 1.442695041f
#define LN2_   0.69314718f

// LDS byte offset of a __shared__ location. Generic pointers to LDS are
// {shared_aperture_hi32 | 32-bit offset}; truncation yields the ds address.
__device__ __forceinline__ unsigned lds_off(const void* p) {
  return (unsigned)(unsigned long long)p;
}

// Scatter edges into per-check rows. counters is UNINITIALIZED scratch: the
// 6 returns per check are consecutive, so ret%6 covers slots 0..5 exactly.
// Row content order is nondeterministic; persistent_kernel sorts each row.
__global__ __launch_bounds__(256) void build_edges_kernel(
    const int* __restrict__ edge_check, unsigned int* __restrict__ counters,
    int* __restrict__ check_edges) {
  int e = blockIdx.x * 256 + threadIdx.x;
  if (e < E_) {
    int r = edge_check[e];
    unsigned int ret = atomicAdd(&counters[r], 1u);
    check_edges[r * DC_ + (ret % 6u)] = e;
  }
}

// Issue 6 back-to-back ds_read_b32 (volatile asm preserves mutual order;
// results NOT ready until an explicit s_waitcnt lgkmcnt).
__device__ __forceinline__ void issue_reads6(float dst[DC_],
                                             const unsigned ra[DC_]) {
  asm volatile("ds_read_b32 %0, %1" : "=v"(dst[0]) : "v"(ra[0]));
  asm volatile("ds_read_b32 %0, %1" : "=v"(dst[1]) : "v"(ra[1]));
  asm volatile("ds_read_b32 %0, %1" : "=v"(dst[2]) : "v"(ra[2]));
  asm volatile("ds_read_b32 %0, %1" : "=v"(dst[3]) : "v"(ra[3]));
  asm volatile("ds_read_b32 %0, %1" : "=v"(dst[4]) : "v"(ra[4]));
  asm volatile("ds_read_b32 %0, %1" : "=v"(dst[5]) : "v"(ra[5]));
}

// One check update: t = (E-q)/(E+q), leave-one-out products, clamp, write
// q_s via asm (6 ds_write_b32, counted in the caller's lgkm budget).
// Bit-identical math/order to R14..R17 (med3 == fmin/fmax clamp, finite y).
__device__ __forceinline__ void compute_check(const float Ev[DC_],
                                              float qo[DC_],
                                              const unsigned wa[DC_]) {
  float t[DC_];
#pragma unroll
  for (int i = 0; i < DC_; i++)
    t[i] = (Ev[i] - qo[i]) * __builtin_amdgcn_rcpf(Ev[i] + qo[i]);
  float loo[DC_];
  float run = 1.0f;
#pragma unroll
  for (int i = 0; i < DC_; i++) { loo[i] = run; run *= t[i]; }
  run = 1.0f;
#pragma unroll
  for (int i = DC_ - 1; i >= 0; i--) { loo[i] *= run; run *= t[i]; }
#pragma unroll
  for (int i = 0; i < DC_; i++) {
    // clamp FIRST (reference clip semantics; keeps 1-y >= 0.001 > 0)
    float y = __builtin_amdgcn_fmed3f(loo[i], -0.999f, 0.999f);
    float qq = (1.0f + y) * __builtin_amdgcn_rcpf(1.0f - y);  // e^{c2v}
    asm volatile("ds_write_b32 %0, %1" :: "v"(wa[i]), "v"(qq));
    qo[i] = qq;
  }
}

// Persistent exp-domain BP: block b decodes batch element b entirely in LDS.
// E_s[v] = e^{tot[v]}, q_s[e] = e^{c2v[e]} (var-major, e = 3v+j).
__global__ __launch_bounds__(THREADS_, 4) void persistent_kernel(
    const float* __restrict__ recv, const int* __restrict__ check_edges,
    float* __restrict__ out) {
  __shared__ float E_s[N_];  // 32 KB, e^{tot}
  __shared__ float q_s[E_];  // 96 KB, e^{c2v}
  const int b = blockIdx.x;
  const int tid = threadIdx.x;
  const float* r = recv + (size_t)b * N_;

  // This thread's 4 check rows -> registers; sort each row ascending
  // (12-comparator optimal network) so the table is deterministic and
  // bit-identical to the sorted-atomic builds of R3..R10.
  int eidx[CPT_][DC_];
#pragma unroll
  for (int c = 0; c < CPT_; c++) {
    int rr = c * THREADS_ + tid;
    int e0 = check_edges[rr * DC_ + 0], e1 = check_edges[rr * DC_ + 1];
    int e2 = check_edges[rr * DC_ + 2], e3 = check_edges[rr * DC_ + 3];
    int e4 = check_edges[rr * DC_ + 4], e5 = check_edges[rr * DC_ + 5];
#define CSWAP(a, b) { int lo = min(a, b), hi = max(a, b); a = lo; b = hi; }
    CSWAP(e0, e5) CSWAP(e1, e3) CSWAP(e2, e4)
    CSWAP(e1, e2) CSWAP(e3, e4)
    CSWAP(e0, e3) CSWAP(e2, e5)
    CSWAP(e0, e1) CSWAP(e2, e3) CSWAP(e4, e5)
    CSWAP(e1, e2) CSWAP(e3, e4)
#undef CSWAP
    eidx[c][0] = e0; eidx[c][1] = e1; eidx[c][2] = e2;
    eidx[c][3] = e3; eidx[c][4] = e4; eidx[c][5] = e5;
  }

  // Precomputed LDS byte addresses (loop-invariant):
  //   raddr = &E_s[e/3] (edge_var[e] == e/3), waddr = &q_s[e].
  // PINNED: the opaque "+v" touch makes each address non-rematerializable,
  // forcing it to stay register-resident across the iter loop (this is the
  // R18 fix for the VGPR=60 remat storm). Live set ~114 <= 128 @ 4 w/SIMD.
  unsigned raddr[CPT_][DC_], waddr[CPT_][DC_];
#pragma unroll
  for (int c = 0; c < CPT_; c++)
#pragma unroll
    for (int i = 0; i < DC_; i++) {
      raddr[c][i] = lds_off(&E_s[(unsigned)eidx[c][i] / 3u]);
      waddr[c][i] = lds_off(&q_s[eidx[c][i]]);
      asm volatile("" : "+v"(raddr[c][i]), "+v"(waddr[c][i]));
    }

  // Own previous c2v output in exp domain: q = e^{c2v}; c2v=0 <=> q=1.
  float qown[CPT_][DC_];
#pragma unroll
  for (int c = 0; c < CPT_; c++)
#pragma unroll
    for (int i = 0; i < DC_; i++) qown[c][i] = 1.0f;

  // e^{llr} per owned var (llr = 2*recv); the only exps in the kernel.
  float e_llr[VPT_];
#pragma unroll
  for (int k = 0; k < VPT_; k++) {
    float llr = 2.0f * r[tid + k * THREADS_];
    e_llr[k] = __builtin_amdgcn_exp2f(llr * LOG2E_);
    E_s[tid + k * THREADS_] = e_llr[k];
  }
  __syncthreads();

  for (int iter = 0; iter < ITERS_; iter++) {
    // ---- check phase: 4-stage per-check pipeline with counted lgkm waits.
    // DS ops complete in-order; issue sequence is
    //   R0(6) R1(6) W0(6) R2(6) W1(6) R3(6) W2(6) W3(6)
    // so the wait budgets below guarantee exactly check c's reads. ----
    float Ev0[DC_], Ev1[DC_], Ev2[DC_], Ev3[DC_];
    issue_reads6(Ev0, raddr[0]);

    issue_reads6(Ev1, raddr[1]);                       // issued 12
    asm volatile("s_waitcnt lgkmcnt(6)" ::: "memory"); // R0 done
    __builtin_amdgcn_sched_barrier(0);
    compute_check(Ev0, qown[0], waddr[0]);             // +W0 -> issued 18

    issue_reads6(Ev2, raddr[2]);                       // issued 24
    asm volatile("s_waitcnt lgkmcnt(12)" ::: "memory");// >=12 done: R1 done
    __builtin_amdgcn_sched_barrier(0);
    compute_check(Ev1, qown[1], waddr[1]);             // +W1 -> issued 30

    issue_reads6(Ev3, raddr[3]);                       // issued 36
    asm volatile("s_waitcnt lgkmcnt(12)" ::: "memory");// >=24 done: R2 done
    __builtin_amdgcn_sched_barrier(0);
    compute_check(Ev2, qown[2], waddr[2]);             // +W2 -> issued 42

    asm volatile("s_waitcnt lgkmcnt(6)" ::: "memory"); // >=36 done: R3 done
    __builtin_amdgcn_sched_barrier(0);
    compute_check(Ev3, qown[3], waddr[3]);             // +W3 -> issued 48

    // Drain OUR asm writes before the barrier: the compiler's own pre-barrier
    // waitcnt only covers ops it tracks, and these are invisible to it.
    asm volatile("s_waitcnt lgkmcnt(0)" ::: "memory");
    __syncthreads();

    // ---- variable phase: E = e^{llr} * q0*q1*q2; q0,q1 paired into one
    // ds_read2_b32 (4B-aligned float2), q2 single. Stride-3 word pattern
    // is 2-way-per-bank max (free); leave in C++. ----
#pragma unroll
    for (int k = 0; k < VPT_; k++) {
      int v = tid + k * THREADS_;
      float2 q01;
      __builtin_memcpy(&q01, &q_s[3 * v], sizeof(float2));
      float q2 = q_s[3 * v + 2];
      E_s[v] = ((e_llr[k] * q01.x) * q01.y) * q2;
    }
    __syncthreads();
  }

  // ---- output: LLR = ln(E); bits = (LLR < 0); [B,N] layout ----
  const size_t BN = (size_t)B_ * N_;
#pragma unroll
  for (int k = 0; k < VPT_; k++) {
    int n = tid + k * THREADS_;
    float val = LN2_ * __builtin_amdgcn_logf(E_s[n]);  // E in [2e-15,5e14]
    out[(size_t)b * N_ + n] = val;
    out[BN + (size_t)b * N_ + n] = (val < 0.0f) ? 1.0f : 0.0f;
  }
}

extern "C" void kernel_launch(void* const* d_in, const int* in_sizes, int n_in,
                              void* d_out, int out_size, void* d_ws,
                              size_t ws_size, hipStream_t stream) {
  const float* recv = (const float*)d_in[0];     // [B, N]
  const int* edge_check = (const int*)d_in[2];   // [E]
  float* out = (float*)d_out;

  char* ws = (char*)d_ws;
  unsigned int* counters = (unsigned int*)ws;           // 16 KB, UNINITIALIZED
  int* check_edges = (int*)(ws + (size_t)R_ * sizeof(unsigned int));  // 96 KB

  build_edges_kernel<<<(E_ + 255) / 256, 256, 0, stream>>>(edge_check, counters,
                                                           check_edges);
  persistent_kernel<<<B_, THREADS_, 0, stream>>>(recv, check_edges, out);
}